// Round 5
// baseline (183.470 us; speedup 1.0000x reference)
//
#include <hip/hip_runtime.h>
#include <math.h>

typedef __attribute__((ext_vector_type(8))) short bf16x8;   // 8 bf16 = 4 VGPRs (MFMA A/B frag)
typedef __attribute__((ext_vector_type(4))) float f32x4;    // MFMA C/D frag
typedef __attribute__((ext_vector_type(4))) unsigned int u32x4;
typedef unsigned short u16;
typedef unsigned int u32;

// Problem: B=8, N=1024, C=768, H=8, hd=96.  BH=64 combined batch-heads.

__device__ __forceinline__ u16 f2b(float f) {               // fp32 -> bf16 RNE
  u32 u = __float_as_uint(f);
  return (u16)((u + 0x7fffu + ((u >> 16) & 1u)) >> 16);
}
__device__ __forceinline__ float b2f(u16 h) {
  return __uint_as_float(((u32)h) << 16);
}
__device__ __forceinline__ int swz(int m) { return (m ^ (m >> 2)) & 3; }

__device__ __forceinline__ void async16(const void* g, void* l) {
  __builtin_amdgcn_global_load_lds((const __attribute__((address_space(1))) u32*)g,
                                   (__attribute__((address_space(3))) u32*)l, 16, 0, 0);
}

// ---------------- prep: cast x, transpose+cast w_qkv and w_proj -------------
__global__ __launch_bounds__(256) void prep_kernel(const float* __restrict__ x,
                                                   const float* __restrict__ w_qkv,
                                                   const float* __restrict__ w_proj,
                                                   u16* __restrict__ xb,
                                                   u16* __restrict__ wqkvT,
                                                   u16* __restrict__ wprojT) {
  __shared__ float t[32][33];
  const int blk = blockIdx.x;
  if (blk < 6144) {                       // cast x -> bf16
    const int idx = blk * 256 + threadIdx.x;
    const float4 v = ((const float4*)x)[idx];
    uint2 o;
    o.x = (u32)f2b(v.x) | ((u32)f2b(v.y) << 16);
    o.y = (u32)f2b(v.z) | ((u32)f2b(v.w) << 16);
    ((uint2*)xb)[idx] = o;
    return;
  }
  const float* in; u16* out; int R, C, bx, by;
  if (blk < 6144 + 1728) {                // w_qkv [768,2304] -> [2304,768]
    const int rem = blk - 6144;
    in = w_qkv; out = wqkvT; R = 768; C = 2304; bx = rem % 72; by = rem / 72;
  } else {                                // w_proj [768,768] -> [768,768]
    const int rem = blk - 6144 - 1728;
    in = w_proj; out = wprojT; R = 768; C = 768; bx = rem % 24; by = rem / 24;
  }
  const int c0 = bx * 32, r0 = by * 32;
  const int tc = threadIdx.x & 31, tr = threadIdx.x >> 5;
#pragma unroll
  for (int j = 0; j < 4; ++j)
    t[tr + j * 8][tc] = in[(size_t)(r0 + tr + j * 8) * C + c0 + tc];
  __syncthreads();
#pragma unroll
  for (int j = 0; j < 4; ++j)
    out[(size_t)(c0 + tr + j * 8) * R + r0 + tc] = f2b(t[tc][tr + j * 8]);
}

// ---------------- 128xNT bf16 MFMA GEMM core (K=768), NT in {64,192} --------
// 512 threads / 8 waves (round-5): wave tile 32 x NT/2, acc[2][JT] = 48 AGPRs
// (was 4 waves, acc[4][JT] = 96 AGPRs -> ~170 total regs -> 2 waves/SIMD, the
// measured 23% occupancy cap).  Halving per-wave acc moves the register
// bracket to 4 waves/SIMD -> 16 waves/CU.  Same block tile, grid, LDS, and
// staging volume -- memory behavior identical by construction.
// Unified LDS granule array per tile: A slots [0,512), B slots [512,512+NT*4).
// Granule XOR swizzle x(m)=(m^(m>>2))&3 keeps frag ds_read_b128 clean while
// staging stays lane-contiguous for global_load_lds (wave-uniform base).
// Double-buffered, one barrier per K-step (neutral vs 2-barrier, kept).
// Staging slots: NFULL full 512-thread slabs + one 256-thread half slab
// (tid<256 is wave-uniform: waves 0-3), so global_load_lds stays legal.
template<int NT>
__device__ __forceinline__ void gemm_core(const u16* __restrict__ A,
                                          const u16* __restrict__ Bt,
                                          int m0, int n0, f32x4 acc[2][NT / 32]) {
  constexpr int JT = NT / 32;
  constexpr int NG = 512 + NT * 4;               // granules per K-tile
  constexpr int NFULL = NG / 512;                // full 512-slot slabs
  constexpr int NREM = NG % 512;                 // 256 for NT in {64,192}
  __shared__ u16 Sm[2 * NG * 8];
  const int tid = threadIdx.x;
  const int w = tid >> 6, lane = tid & 63;
  const int i15 = lane & 15, quad = lane >> 4;
  const int wm = (w >> 1) * 32, wn = (w & 1) * (NT / 2);
  const int sw = quad ^ swz(i15);

#pragma unroll
  for (int i = 0; i < 2; ++i)
#pragma unroll
    for (int j = 0; j < JT; ++j) acc[i][j] = (f32x4){0.f, 0.f, 0.f, 0.f};

  // per-inst global source pointers at k0=0 (advance +32 per K-step)
  const u16* gsrc[NFULL + 1];
#pragma unroll
  for (int inst = 0; inst <= NFULL; ++inst) {
    const int s = inst * 512 + tid;              // granule slot (per lane)
    if (s >= NG) { gsrc[inst] = A; continue; }   // inactive (guarded below)
    if (s < 512) {                               // A region
      const int m = s >> 2, e = s & 3;
      gsrc[inst] = A + ((size_t)(m0 + m) * 768 + (e ^ swz(m)) * 8);
    } else {                                     // B region
      const int s2 = s - 512;
      const int n = s2 >> 2, e = s2 & 3;
      gsrc[inst] = Bt + ((size_t)(n0 + n) * 768 + (e ^ swz(n)) * 8);
    }
  }

  // prologue: stage K-tile 0 into buf 0
#pragma unroll
  for (int inst = 0; inst < NFULL; ++inst)
    async16(gsrc[inst], (void*)(Sm + (size_t)(inst * 512 + w * 64) * 8));
  if (tid < NREM)                                // waves 0-3 only (wave-uniform)
    async16(gsrc[NFULL], (void*)(Sm + (size_t)(NFULL * 512 + w * 64) * 8));

  for (int t = 0; t < 24; ++t) {
    __syncthreads();                             // implicit vmcnt(0): buf[t&1] ready
    const u16* buf = Sm + (size_t)(t & 1) * NG * 8;
    if (t < 23) {                                // stage t+1 into other buffer
      u16* dst = Sm + (size_t)((t + 1) & 1) * NG * 8;
#pragma unroll
      for (int inst = 0; inst <= NFULL; ++inst) gsrc[inst] += 32;
#pragma unroll
      for (int inst = 0; inst < NFULL; ++inst)
        async16(gsrc[inst], (void*)(dst + (size_t)(inst * 512 + w * 64) * 8));
      if (tid < NREM)
        async16(gsrc[NFULL], (void*)(dst + (size_t)(NFULL * 512 + w * 64) * 8));
    }
    bf16x8 af[2], bf[JT];
#pragma unroll
    for (int i = 0; i < 2; ++i)
      af[i] = *(const bf16x8*)(buf + ((size_t)(wm + i * 16 + i15) * 4 + sw) * 8);
#pragma unroll
    for (int j = 0; j < JT; ++j)
      bf[j] = *(const bf16x8*)(buf + ((size_t)512 + (wn + j * 16 + i15) * 4 + sw) * 8);
#pragma unroll
    for (int i = 0; i < 2; ++i)
#pragma unroll
      for (int j = 0; j < JT; ++j)
        acc[i][j] = __builtin_amdgcn_mfma_f32_16x16x32_bf16(af[i], bf[j], acc[i][j], 0, 0, 0);
  }
}

// ---------------- qkv GEMM + fused L2norm/temp epilogue ---------------------
// Tile 128x192, 8 waves: wave = 32 rows x 96 cols = exactly 1 head's width ->
// sumsq stays in-thread over jt + shfl_xor(1,2,4,8) (16 lanes sharing quad).
// q gets temp[h] folded; v written transposed (packed).
__global__ __launch_bounds__(512, 4) void qkv_gemm_kernel(
    const u16* __restrict__ xb, const u16* __restrict__ wT,
    const float* __restrict__ temp,
    u16* __restrict__ q, u16* __restrict__ k, u16* __restrict__ vT) {
  f32x4 acc[2][6];
  const int bid = blockIdx.x;                 // 768 blocks
  const int xcd = bid & 7, slot = bid >> 3;   // 96 slots per XCD
  const int mb = xcd * 8 + slot / 12, nb = slot % 12;
  const int m0 = mb * 128, n0 = nb * 192;
  gemm_core<192>(xb, wT, m0, n0, acc);

  const int tid = threadIdx.x, w = tid >> 6, lane = tid & 63;
  const int i15 = lane & 15, quad = lane >> 4;
  const int wm = (w >> 1) * 32;
  const int three = nb >> 2;                  // 0=q, 1=k, 2=v
  const int h = ((nb & 3) << 1) + (w & 1);    // wave-uniform head

  if (three < 2) {
    u16* dst = three ? k : q;
    const float sc_extra = three ? 1.f : temp[h];
#pragma unroll
    for (int it = 0; it < 2; ++it) {
#pragma unroll
      for (int r = 0; r < 4; ++r) {
        float s = 0.f;
#pragma unroll
        for (int jt = 0; jt < 6; ++jt) s += acc[it][jt][r] * acc[it][jt][r];
        s += __shfl_xor(s, 1); s += __shfl_xor(s, 2);
        s += __shfl_xor(s, 4); s += __shfl_xor(s, 8);
        const float scale = sc_extra / fmaxf(sqrtf(s), 1e-12f);
        const int m = m0 + wm + it * 16 + quad * 4 + r;
        const int b = m >> 10, n = m & 1023;
        u16* rowp = dst + ((size_t)(b * 8 + h) * 1024 + n) * 96;
#pragma unroll
        for (int jt = 0; jt < 6; ++jt)
          rowp[jt * 16 + i15] = f2b(acc[it][jt][r] * scale);
      }
    }
  } else {
#pragma unroll
    for (int it = 0; it < 2; ++it) {
      const int mb4 = m0 + wm + it * 16 + quad * 4;
      const int b = mb4 >> 10, nbase = mb4 & 1023;
#pragma unroll
      for (int jt = 0; jt < 6; ++jt) {
        const int d = jt * 16 + i15;
        uint2 pk;
        pk.x = (u32)f2b(acc[it][jt][0]) | ((u32)f2b(acc[it][jt][1]) << 16);
        pk.y = (u32)f2b(acc[it][jt][2]) | ((u32)f2b(acc[it][jt][3]) << 16);
        *(uint2*)(vT + ((size_t)(b * 8 + h) * 96 + d) * 1024 + nbase) = pk;
      }
    }
  }
}

// ---------------- fused attention, bf16 MFMA, no-max online softmax ---------
// 128 q-rows/block, grid 512, bh = blockIdx&63 (8 q-blocks of one bh share an
// XCD; K/V L2-resident ~3 MB/XCD).  512 threads = 8 waves x 16 q-rows.
// global_load_lds staging into DOUBLE-BUFFERED KV region, one barrier/tile.
// LDS: 2 x 12288 u16 KV buffers + 8 x 1024 u16 per-wave P = 64 KB -> 2 blk/CU.
// S^T = K*Q^T (C-regs = 4 consecutive keys) -> exp -> packed b64 into per-wave
// Ps -> PV with A=P, B=V^T. swz() granule XOR layouts.
__global__ __launch_bounds__(512, 4) void attn_kernel(
    const u16* __restrict__ q, const u16* __restrict__ kk,
    const u16* __restrict__ vT, u16* __restrict__ ctx) {
  __shared__ u16 smem[32768];   // [0,12288) buf0; [12288,24576) buf1; [24576,32768) P
  const int tid = threadIdx.x, w = tid >> 6, lane = tid & 63;
  const int i15 = lane & 15, quad = lane >> 4;
  const int xs = swz(i15);
  const int bh = blockIdx.x & 63, qbase = (blockIdx.x >> 6) * 128;
  const int b = bh >> 3, h = bh & 7;
  u16* Pw = smem + 24576 + w * 1024;   // per-wave P: 128 granules (16 rows x 64 keys)

  bf16x8 qf[3];
  {
    const int qrow = qbase + w * 16 + i15;
    const u16* qp = q + ((size_t)bh * 1024 + qrow) * 96 + quad * 8;
#pragma unroll
    for (int c = 0; c < 3; ++c) qf[c] = *(const bf16x8*)(qp + c * 32);
  }

  // Staging: 1536 granules/tile (K 768 + V 768), 3 async16 per thread.
  // Granule->global mapping is the inverse of the read-side formulas:
  //   K granule s<768:  c=s>>8, key=(s&255)>>2, qd=s&3 -> row key, octet c*4+(qd^swz(key))
  //   V granule s2:     r=s2>>2, c2=r>=96, d=r-96*c2, qd=s2&3 -> row d, key col c2*32+(qd^swz(d))*8
  const u16* gsrc[3]; int gstep[3];
#pragma unroll
  for (int inst = 0; inst < 3; ++inst) {
    const int s = inst * 512 + tid;
    if (s < 768) {
      const int key6 = (s & 255) >> 2, c = s >> 8;
      const int e = c * 4 + ((s & 3) ^ swz(key6));
      gsrc[inst] = kk + ((size_t)bh * 1024 + key6) * 96 + e * 8;
      gstep[inst] = 64 * 96;                 // +64 key rows per tile
    } else {
      const int s2 = s - 768, r = s2 >> 2;
      const int c2 = (r >= 96), d = r - 96 * c2;
      gsrc[inst] = vT + ((size_t)bh * 96 + d) * 1024 + c2 * 32 + ((s2 & 3) ^ swz(d)) * 8;
      gstep[inst] = 64;                      // +64 key cols per tile
    }
  }

  // prologue: stage tile 0 into buf0 (LDS dest is wave-uniform base + lane*16)
#pragma unroll
  for (int inst = 0; inst < 3; ++inst)
    async16(gsrc[inst], (void*)(smem + (size_t)(inst * 512 + w * 64) * 8));

  f32x4 o[6];
#pragma unroll
  for (int dt = 0; dt < 6; ++dt) o[dt] = (f32x4){0.f, 0.f, 0.f, 0.f};
  float l = 0.f;

  for (int t = 0; t < 16; ++t) {
    __syncthreads();                         // implicit vmcnt(0): buf[t&1] ready
    const u16* KVs = smem + (t & 1) * 12288;
    if (t < 15) {                            // stage t+1 into the other buffer
      u16* dst = smem + ((t + 1) & 1) * 12288;
#pragma unroll
      for (int inst = 0; inst < 3; ++inst) {
        gsrc[inst] += gstep[inst];
        async16(gsrc[inst], (void*)(dst + (size_t)(inst * 512 + w * 64) * 8));
      }
    }
    // ---- S^T phase ----
#pragma unroll
    for (int kt = 0; kt < 4; ++kt) {
      bf16x8 af[3];
#pragma unroll
      for (int c = 0; c < 3; ++c)
        af[c] = *(const bf16x8*)(KVs + ((size_t)((c * 64 + kt * 16 + i15) * 4) + (quad ^ xs)) * 8);
      f32x4 s = (f32x4){0.f, 0.f, 0.f, 0.f};
#pragma unroll
      for (int c = 0; c < 3; ++c)
        s = __builtin_amdgcn_mfma_f32_16x16x32_bf16(af[c], qf[c], s, 0, 0, 0);
      const float e0 = __expf(s[0]), e1 = __expf(s[1]);
      const float e2 = __expf(s[2]), e3 = __expf(s[3]);
      l += (e0 + e1) + (e2 + e3);
      uint2 pk;
      pk.x = (u32)f2b(e0) | ((u32)f2b(e1) << 16);
      pk.y = (u32)f2b(e2) | ((u32)f2b(e3) << 16);
      const int pg = (kt & 1) * 2 + (quad >> 1);
      *(uint2*)(Pw + (size_t)(((kt >> 1) * 16 + i15) * 4 + (pg ^ xs)) * 8
                    + (quad & 1) * 4) = pk;
    }
    // ---- PV phase ----
#pragma unroll
    for (int c2 = 0; c2 < 2; ++c2) {
      const bf16x8 pa = *(const bf16x8*)(Pw + (size_t)((c2 * 16 + i15) * 4 + (quad ^ xs)) * 8);
#pragma unroll
      for (int dt = 0; dt < 6; ++dt) {
        const bf16x8 vb = *(const bf16x8*)(KVs +
            ((size_t)(768 + (c2 * 96 + dt * 16 + i15) * 4) + (quad ^ xs)) * 8);
        o[dt] = __builtin_amdgcn_mfma_f32_16x16x32_bf16(pa, vb, o[dt], 0, 0, 0);
      }
    }
  }

  l += __shfl_xor(l, 16); l += __shfl_xor(l, 32);
  __syncthreads();                       // all waves done with KVs/Pw regions
  u16* scr = smem + w * 1664;            // 16 rows x stride 104 (per-wave)
#pragma unroll
  for (int r = 0; r < 4; ++r) {
    const float linv = 1.f / __shfl(l, quad * 4 + r);
    const int row16 = quad * 4 + r;
#pragma unroll
    for (int dt = 0; dt < 6; ++dt)
      scr[row16 * 104 + dt * 16 + i15] = f2b(o[dt][r] * linv);
  }
#pragma unroll
  for (int jj = 0; jj < 3; ++jj) {
    const int id = jj * 64 + lane;
    const int row16 = id / 12, g = id - row16 * 12;
    const int grow = b * 1024 + qbase + w * 16 + row16;
    *(uint4*)(ctx + (size_t)grow * 768 + h * 96 + g * 8) =
        *(const uint4*)(scr + row16 * 104 + g * 8);
  }
}

// ---------------- proj GEMM: 128x64 tiles, ctx @ wT + bias -> out fp32 ------
// 8 waves, wave tile 32x32, acc[2][2] = 16 AGPRs -> min-6-waves/EU bound fits
// 3 blocks/CU exactly (grid 768).
__global__ __launch_bounds__(512, 6) void proj_gemm_kernel(
    const u16* __restrict__ ctx, const u16* __restrict__ wT,
    const float* __restrict__ bias, float* __restrict__ out) {
  f32x4 acc[2][2];
  const int bid = blockIdx.x;                 // 768 blocks = 3/CU exact
  const int xcd = bid & 7, slot = bid >> 3;   // 96 slots per XCD
  const int mb = xcd * 8 + slot / 12, nb = slot % 12;
  const int m0 = mb * 128, n0 = nb * 64;
  gemm_core<64>(ctx, wT, m0, n0, acc);

  const int tid = threadIdx.x, w = tid >> 6, lane = tid & 63;
  const int i15 = lane & 15, quad = lane >> 4;
  const int wm = (w >> 1) * 32, wn = (w & 1) * 32;
#pragma unroll
  for (int jt = 0; jt < 2; ++jt) {
    const int c = n0 + wn + jt * 16 + i15;
    const float bb = bias[c];
#pragma unroll
    for (int it = 0; it < 2; ++it) {
#pragma unroll
      for (int r = 0; r < 4; ++r) {
        const int m = m0 + wm + it * 16 + quad * 4 + r;
        out[(size_t)m * 768 + c] = acc[it][jt][r] + bb;
      }
    }
  }
}

// ---------------- host launcher --------------------------------------------
extern "C" void kernel_launch(void* const* d_in, const int* in_sizes, int n_in,
                              void* d_out, int out_size, void* d_ws, size_t ws_size,
                              hipStream_t stream) {
  const float* x      = (const float*)d_in[0];   // [8,1024,768]
  const float* w_qkv  = (const float*)d_in[1];   // [768,2304]
  const float* temp   = (const float*)d_in[2];   // [8]
  const float* w_proj = (const float*)d_in[3];   // [768,768]
  const float* b_proj = (const float*)d_in[4];   // [768]

  u16* ws      = (u16*)d_ws;
  u16* xb      = ws;                     // 8192*768
  u16* wqkvT   = xb + 6291456;           // 2304*768
  u16* qb      = wqkvT + 1769472;        // 64*1024*96
  u16* kb      = qb + 6291456;
  u16* vTb     = kb + 6291456;           // 64*96*1024 (transposed)
  u16* ctxb    = vTb + 6291456;          // 8192*768
  u16* wprojT  = ctxb + 6291456;         // 768*768

  prep_kernel<<<8448, 256, 0, stream>>>(x, w_qkv, w_proj, xb, wqkvT, wprojT);
  qkv_gemm_kernel<<<768, 512, 0, stream>>>(xb, wqkvT, temp, qb, kb, vTb);
  attn_kernel<<<512, 512, 0, stream>>>(qb, kb, vTb, ctxb);
  proj_gemm_kernel<<<768, 512, 0, stream>>>(ctxb, wprojT, b_proj, (float*)d_out);
}

// Round 6
// 180.634 us; speedup vs baseline: 1.0157x; 1.0157x over previous
//
#include <hip/hip_runtime.h>
#include <math.h>

typedef __attribute__((ext_vector_type(8))) short bf16x8;   // 8 bf16 = 4 VGPRs (MFMA A/B frag)
typedef __attribute__((ext_vector_type(4))) float f32x4;    // MFMA C/D frag
typedef __attribute__((ext_vector_type(4))) unsigned int u32x4;
typedef unsigned short u16;
typedef unsigned int u32;

// Problem: B=8, N=1024, C=768, H=8, hd=96.  BH=64 combined batch-heads.

__device__ __forceinline__ u16 f2b(float f) {               // fp32 -> bf16 RNE
  u32 u = __float_as_uint(f);
  return (u16)((u + 0x7fffu + ((u >> 16) & 1u)) >> 16);
}
__device__ __forceinline__ float b2f(u16 h) {
  return __uint_as_float(((u32)h) << 16);
}
__device__ __forceinline__ int swz(int m) { return (m ^ (m >> 2)) & 3; }

__device__ __forceinline__ void async16(const void* g, void* l) {
  __builtin_amdgcn_global_load_lds((const __attribute__((address_space(1))) u32*)g,
                                   (__attribute__((address_space(3))) u32*)l, 16, 0, 0);
}

// counted vmcnt waits (immediate must be literal in the asm string)
template<int N> __device__ __forceinline__ void wait_vmcnt();
template<> __device__ __forceinline__ void wait_vmcnt<0>() {
  asm volatile("s_waitcnt vmcnt(0)" ::: "memory");
}
template<> __device__ __forceinline__ void wait_vmcnt<3>() {
  asm volatile("s_waitcnt vmcnt(3)" ::: "memory");
}
template<> __device__ __forceinline__ void wait_vmcnt<5>() {
  asm volatile("s_waitcnt vmcnt(5)" ::: "memory");
}

// ---------------- prep: cast x, transpose+cast w_qkv and w_proj -------------
__global__ __launch_bounds__(256) void prep_kernel(const float* __restrict__ x,
                                                   const float* __restrict__ w_qkv,
                                                   const float* __restrict__ w_proj,
                                                   u16* __restrict__ xb,
                                                   u16* __restrict__ wqkvT,
                                                   u16* __restrict__ wprojT) {
  __shared__ float t[32][33];
  const int blk = blockIdx.x;
  if (blk < 6144) {                       // cast x -> bf16
    const int idx = blk * 256 + threadIdx.x;
    const float4 v = ((const float4*)x)[idx];
    uint2 o;
    o.x = (u32)f2b(v.x) | ((u32)f2b(v.y) << 16);
    o.y = (u32)f2b(v.z) | ((u32)f2b(v.w) << 16);
    ((uint2*)xb)[idx] = o;
    return;
  }
  const float* in; u16* out; int R, C, bx, by;
  if (blk < 6144 + 1728) {                // w_qkv [768,2304] -> [2304,768]
    const int rem = blk - 6144;
    in = w_qkv; out = wqkvT; R = 768; C = 2304; bx = rem % 72; by = rem / 72;
  } else {                                // w_proj [768,768] -> [768,768]
    const int rem = blk - 6144 - 1728;
    in = w_proj; out = wprojT; R = 768; C = 768; bx = rem % 24; by = rem / 24;
  }
  const int c0 = bx * 32, r0 = by * 32;
  const int tc = threadIdx.x & 31, tr = threadIdx.x >> 5;
#pragma unroll
  for (int j = 0; j < 4; ++j)
    t[tr + j * 8][tc] = in[(size_t)(r0 + tr + j * 8) * C + c0 + tc];
  __syncthreads();
#pragma unroll
  for (int j = 0; j < 4; ++j)
    out[(size_t)(c0 + tr + j * 8) * R + r0 + tc] = f2b(t[tc][tr + j * 8]);
}

// ---------------- 128xNT bf16 MFMA GEMM core (K=768), NT in {64,192} --------
// 256 threads / 4 waves, wave tile 64 x NT/2 (round-4 config; the 8-wave
// split regressed: FETCH +40% from reduced same-mb block co-residency).
// Round-6: COUNTED-VMCNT 3-BUFFER PIPELINE (T4, m218: counted-vs-drain is
// the gain).  __syncthreads' implicit vmcnt(0) forced every K-step's stage
// loads to land within ONE K-step of compute -- an HBM straggler stalled all
// waves.  Now: raw s_barrier + s_waitcnt vmcnt(NINST): tile t's loads must
// be done, tile t+1's stay in flight -> loads get TWO K-steps to land.
// Safety: buffers t, t+1, t+2 distinct mod 3; cross-wave reads of buffer
// (t-1)%3 completed before barrier t (MFMA operand use forces lgkmcnt drain
// in program order); global_load_lds is vmcnt-only and no other vmem ops
// exist in the loop, so the count is exact.
// Unified LDS granule array per tile: A slots [0,512), B slots [512,512+NT*4).
// Granule XOR swizzle x(m)=(m^(m>>2))&3 keeps frag ds_read_b128 clean while
// staging stays lane-contiguous for global_load_lds (wave-uniform base).
template<int NT>
__device__ __forceinline__ void gemm_core(const u16* __restrict__ A,
                                          const u16* __restrict__ Bt,
                                          int m0, int n0, f32x4 acc[4][NT / 32]) {
  constexpr int JT = NT / 32;
  constexpr int NG = 512 + NT * 4;               // granules per K-tile
  constexpr int NINST = NG / 256;                // async16 per thread per tile
  __shared__ u16 Sm[3 * NG * 8];
  const int tid = threadIdx.x;
  const int w = tid >> 6, lane = tid & 63;
  const int i15 = lane & 15, quad = lane >> 4;
  const int wm = (w >> 1) * 64, wn = (w & 1) * (NT / 2);
  const int sw = quad ^ swz(i15);

#pragma unroll
  for (int i = 0; i < 4; ++i)
#pragma unroll
    for (int j = 0; j < JT; ++j) acc[i][j] = (f32x4){0.f, 0.f, 0.f, 0.f};

  // per-inst global source pointers at k0=0 (advance +32 per staged tile)
  const u16* gsrc[NINST];
#pragma unroll
  for (int inst = 0; inst < NINST; ++inst) {
    const int s = inst * 256 + tid;              // granule slot (per lane)
    if (s < 512) {                               // A region
      const int m = s >> 2, e = s & 3;
      gsrc[inst] = A + ((size_t)(m0 + m) * 768 + (e ^ swz(m)) * 8);
    } else {                                     // B region
      const int s2 = s - 512;
      const int n = s2 >> 2, e = s2 & 3;
      gsrc[inst] = Bt + ((size_t)(n0 + n) * 768 + (e ^ swz(n)) * 8);
    }
  }

  auto stage = [&](int bsel) {
#pragma unroll
    for (int inst = 0; inst < NINST; ++inst) {
      async16(gsrc[inst], (void*)(Sm + ((size_t)bsel * NG + inst * 256 + w * 64) * 8));
      gsrc[inst] += 32;
    }
  };

  // prologue: tiles 0 and 1 in flight (out = 2*NINST)
  stage(0);
  stage(1);

  for (int t = 0; t < 24; ++t) {
    if (t < 23) wait_vmcnt<NINST>();             // tile t landed; t+1 in flight
    else        wait_vmcnt<0>();                 // last tile: full drain
    __builtin_amdgcn_s_barrier();                // all waves' t-loads visible
    __builtin_amdgcn_sched_barrier(0);           // pin: nothing hoists above
    if (t < 22) stage((t + 2) % 3);              // out back to 2*NINST
    const u16* buf = Sm + (size_t)(t % 3) * NG * 8;
    bf16x8 af[4], bf[JT];
#pragma unroll
    for (int i = 0; i < 4; ++i)
      af[i] = *(const bf16x8*)(buf + ((size_t)(wm + i * 16 + i15) * 4 + sw) * 8);
#pragma unroll
    for (int j = 0; j < JT; ++j)
      bf[j] = *(const bf16x8*)(buf + ((size_t)512 + (wn + j * 16 + i15) * 4 + sw) * 8);
#pragma unroll
    for (int i = 0; i < 4; ++i)
#pragma unroll
      for (int j = 0; j < JT; ++j)
        acc[i][j] = __builtin_amdgcn_mfma_f32_16x16x32_bf16(af[i], bf[j], acc[i][j], 0, 0, 0);
  }
}

// ---------------- qkv GEMM + fused L2norm/temp epilogue ---------------------
// Tile 128x192: N-tile = exactly 2 heads -> each wave owns one head's full
// 96-d rows. Rows live in 16 lanes sharing quad -> sumsq = in-thread over jt
// + shfl_xor(1,2,4,8). q gets temp[h] folded; v written transposed (packed).
// LDS 60KB (3 buffers) -> 2 blocks/CU.
__global__ __launch_bounds__(256, 2) void qkv_gemm_kernel(
    const u16* __restrict__ xb, const u16* __restrict__ wT,
    const float* __restrict__ temp,
    u16* __restrict__ q, u16* __restrict__ k, u16* __restrict__ vT) {
  f32x4 acc[4][6];
  const int bid = blockIdx.x;                 // 768 blocks
  const int xcd = bid & 7, slot = bid >> 3;   // 96 slots per XCD
  const int mb = xcd * 8 + slot / 12, nb = slot % 12;
  const int m0 = mb * 128, n0 = nb * 192;
  gemm_core<192>(xb, wT, m0, n0, acc);

  const int tid = threadIdx.x, w = tid >> 6, lane = tid & 63;
  const int i15 = lane & 15, quad = lane >> 4;
  const int wm = (w >> 1) * 64;
  const int three = nb >> 2;                  // 0=q, 1=k, 2=v
  const int h = ((nb & 3) << 1) + (w & 1);    // wave-uniform head

  if (three < 2) {
    u16* dst = three ? k : q;
    const float sc_extra = three ? 1.f : temp[h];
#pragma unroll
    for (int it = 0; it < 4; ++it) {
#pragma unroll
      for (int r = 0; r < 4; ++r) {
        float s = 0.f;
#pragma unroll
        for (int jt = 0; jt < 6; ++jt) s += acc[it][jt][r] * acc[it][jt][r];
        s += __shfl_xor(s, 1); s += __shfl_xor(s, 2);
        s += __shfl_xor(s, 4); s += __shfl_xor(s, 8);
        const float scale = sc_extra / fmaxf(sqrtf(s), 1e-12f);
        const int m = m0 + wm + it * 16 + quad * 4 + r;
        const int b = m >> 10, n = m & 1023;
        u16* rowp = dst + ((size_t)(b * 8 + h) * 1024 + n) * 96;
#pragma unroll
        for (int jt = 0; jt < 6; ++jt)
          rowp[jt * 16 + i15] = f2b(acc[it][jt][r] * scale);
      }
    }
  } else {
#pragma unroll
    for (int it = 0; it < 4; ++it) {
      const int mb4 = m0 + wm + it * 16 + quad * 4;
      const int b = mb4 >> 10, nbase = mb4 & 1023;
#pragma unroll
      for (int jt = 0; jt < 6; ++jt) {
        const int d = jt * 16 + i15;
        uint2 pk;
        pk.x = (u32)f2b(acc[it][jt][0]) | ((u32)f2b(acc[it][jt][1]) << 16);
        pk.y = (u32)f2b(acc[it][jt][2]) | ((u32)f2b(acc[it][jt][3]) << 16);
        *(uint2*)(vT + ((size_t)(b * 8 + h) * 96 + d) * 1024 + nbase) = pk;
      }
    }
  }
}

// ---------------- fused attention, bf16 MFMA, no-max online softmax ---------
// 128 q-rows/block, grid 512, bh = blockIdx&63 (8 q-blocks of one bh share an
// XCD; K/V L2-resident ~3 MB/XCD).  512 threads = 8 waves x 16 q-rows.
// global_load_lds staging into DOUBLE-BUFFERED KV region, one barrier/tile.
// LDS: 2 x 12288 u16 KV buffers + 8 x 1024 u16 per-wave P = 64 KB -> 2 blk/CU.
// S^T = K*Q^T (C-regs = 4 consecutive keys) -> exp -> packed b64 into per-wave
// Ps -> PV with A=P, B=V^T. swz() granule XOR layouts.
__global__ __launch_bounds__(512, 4) void attn_kernel(
    const u16* __restrict__ q, const u16* __restrict__ kk,
    const u16* __restrict__ vT, u16* __restrict__ ctx) {
  __shared__ u16 smem[32768];   // [0,12288) buf0; [12288,24576) buf1; [24576,32768) P
  const int tid = threadIdx.x, w = tid >> 6, lane = tid & 63;
  const int i15 = lane & 15, quad = lane >> 4;
  const int xs = swz(i15);
  const int bh = blockIdx.x & 63, qbase = (blockIdx.x >> 6) * 128;
  const int b = bh >> 3, h = bh & 7;
  u16* Pw = smem + 24576 + w * 1024;   // per-wave P: 128 granules (16 rows x 64 keys)

  bf16x8 qf[3];
  {
    const int qrow = qbase + w * 16 + i15;
    const u16* qp = q + ((size_t)bh * 1024 + qrow) * 96 + quad * 8;
#pragma unroll
    for (int c = 0; c < 3; ++c) qf[c] = *(const bf16x8*)(qp + c * 32);
  }

  // Staging: 1536 granules/tile (K 768 + V 768), 3 async16 per thread.
  // Granule->global mapping is the inverse of the read-side formulas:
  //   K granule s<768:  c=s>>8, key=(s&255)>>2, qd=s&3 -> row key, octet c*4+(qd^swz(key))
  //   V granule s2:     r=s2>>2, c2=r>=96, d=r-96*c2, qd=s2&3 -> row d, key col c2*32+(qd^swz(d))*8
  const u16* gsrc[3]; int gstep[3];
#pragma unroll
  for (int inst = 0; inst < 3; ++inst) {
    const int s = inst * 512 + tid;
    if (s < 768) {
      const int key6 = (s & 255) >> 2, c = s >> 8;
      const int e = c * 4 + ((s & 3) ^ swz(key6));
      gsrc[inst] = kk + ((size_t)bh * 1024 + key6) * 96 + e * 8;
      gstep[inst] = 64 * 96;                 // +64 key rows per tile
    } else {
      const int s2 = s - 768, r = s2 >> 2;
      const int c2 = (r >= 96), d = r - 96 * c2;
      gsrc[inst] = vT + ((size_t)bh * 96 + d) * 1024 + c2 * 32 + ((s2 & 3) ^ swz(d)) * 8;
      gstep[inst] = 64;                      // +64 key cols per tile
    }
  }

  // prologue: stage tile 0 into buf0 (LDS dest is wave-uniform base + lane*16)
#pragma unroll
  for (int inst = 0; inst < 3; ++inst)
    async16(gsrc[inst], (void*)(smem + (size_t)(inst * 512 + w * 64) * 8));

  f32x4 o[6];
#pragma unroll
  for (int dt = 0; dt < 6; ++dt) o[dt] = (f32x4){0.f, 0.f, 0.f, 0.f};
  float l = 0.f;

  for (int t = 0; t < 16; ++t) {
    __syncthreads();                         // implicit vmcnt(0): buf[t&1] ready
    const u16* KVs = smem + (t & 1) * 12288;
    if (t < 15) {                            // stage t+1 into the other buffer
      u16* dst = smem + ((t + 1) & 1) * 12288;
#pragma unroll
      for (int inst = 0; inst < 3; ++inst) {
        gsrc[inst] += gstep[inst];
        async16(gsrc[inst], (void*)(dst + (size_t)(inst * 512 + w * 64) * 8));
      }
    }
    // ---- S^T phase ----
#pragma unroll
    for (int kt = 0; kt < 4; ++kt) {
      bf16x8 af[3];
#pragma unroll
      for (int c = 0; c < 3; ++c)
        af[c] = *(const bf16x8*)(KVs + ((size_t)((c * 64 + kt * 16 + i15) * 4) + (quad ^ xs)) * 8);
      f32x4 s = (f32x4){0.f, 0.f, 0.f, 0.f};
#pragma unroll
      for (int c = 0; c < 3; ++c)
        s = __builtin_amdgcn_mfma_f32_16x16x32_bf16(af[c], qf[c], s, 0, 0, 0);
      const float e0 = __expf(s[0]), e1 = __expf(s[1]);
      const float e2 = __expf(s[2]), e3 = __expf(s[3]);
      l += (e0 + e1) + (e2 + e3);
      uint2 pk;
      pk.x = (u32)f2b(e0) | ((u32)f2b(e1) << 16);
      pk.y = (u32)f2b(e2) | ((u32)f2b(e3) << 16);
      const int pg = (kt & 1) * 2 + (quad >> 1);
      *(uint2*)(Pw + (size_t)(((kt >> 1) * 16 + i15) * 4 + (pg ^ xs)) * 8
                    + (quad & 1) * 4) = pk;
    }
    // ---- PV phase ----
#pragma unroll
    for (int c2 = 0; c2 < 2; ++c2) {
      const bf16x8 pa = *(const bf16x8*)(Pw + (size_t)((c2 * 16 + i15) * 4 + (quad ^ xs)) * 8);
#pragma unroll
      for (int dt = 0; dt < 6; ++dt) {
        const bf16x8 vb = *(const bf16x8*)(KVs +
            ((size_t)(768 + (c2 * 96 + dt * 16 + i15) * 4) + (quad ^ xs)) * 8);
        o[dt] = __builtin_amdgcn_mfma_f32_16x16x32_bf16(pa, vb, o[dt], 0, 0, 0);
      }
    }
  }

  l += __shfl_xor(l, 16); l += __shfl_xor(l, 32);
  __syncthreads();                       // all waves done with KVs/Pw regions
  u16* scr = smem + w * 1664;            // 16 rows x stride 104 (per-wave)
#pragma unroll
  for (int r = 0; r < 4; ++r) {
    const float linv = 1.f / __shfl(l, quad * 4 + r);
    const int row16 = quad * 4 + r;
#pragma unroll
    for (int dt = 0; dt < 6; ++dt)
      scr[row16 * 104 + dt * 16 + i15] = f2b(o[dt][r] * linv);
  }
#pragma unroll
  for (int jj = 0; jj < 3; ++jj) {
    const int id = jj * 64 + lane;
    const int row16 = id / 12, g = id - row16 * 12;
    const int grow = b * 1024 + qbase + w * 16 + row16;
    *(uint4*)(ctx + (size_t)grow * 768 + h * 96 + g * 8) =
        *(const uint4*)(scr + row16 * 104 + g * 8);
  }
}

// ---------------- proj GEMM: 128x64 tiles, ctx @ wT + bias -> out fp32 ------
// LDS 36KB (3 buffers) -> 4 blocks/CU.
__global__ __launch_bounds__(256, 4) void proj_gemm_kernel(
    const u16* __restrict__ ctx, const u16* __restrict__ wT,
    const float* __restrict__ bias, float* __restrict__ out) {
  f32x4 acc[4][2];
  const int bid = blockIdx.x;                 // 768 blocks
  const int xcd = bid & 7, slot = bid >> 3;   // 96 slots per XCD
  const int mb = xcd * 8 + slot / 12, nb = slot % 12;
  const int m0 = mb * 128, n0 = nb * 64;
  gemm_core<64>(ctx, wT, m0, n0, acc);

  const int tid = threadIdx.x, w = tid >> 6, lane = tid & 63;
  const int i15 = lane & 15, quad = lane >> 4;
  const int wm = (w >> 1) * 64, wn = (w & 1) * 32;
#pragma unroll
  for (int jt = 0; jt < 2; ++jt) {
    const int c = n0 + wn + jt * 16 + i15;
    const float bb = bias[c];
#pragma unroll
    for (int it = 0; it < 4; ++it) {
#pragma unroll
      for (int r = 0; r < 4; ++r) {
        const int m = m0 + wm + it * 16 + quad * 4 + r;
        out[(size_t)m * 768 + c] = acc[it][jt][r] + bb;
      }
    }
  }
}

// ---------------- host launcher --------------------------------------------
extern "C" void kernel_launch(void* const* d_in, const int* in_sizes, int n_in,
                              void* d_out, int out_size, void* d_ws, size_t ws_size,
                              hipStream_t stream) {
  const float* x      = (const float*)d_in[0];   // [8,1024,768]
  const float* w_qkv  = (const float*)d_in[1];   // [768,2304]
  const float* temp   = (const float*)d_in[2];   // [8]
  const float* w_proj = (const float*)d_in[3];   // [768,768]
  const float* b_proj = (const float*)d_in[4];   // [768]

  u16* ws      = (u16*)d_ws;
  u16* xb      = ws;                     // 8192*768
  u16* wqkvT   = xb + 6291456;           // 2304*768
  u16* qb      = wqkvT + 1769472;        // 64*1024*96
  u16* kb      = qb + 6291456;
  u16* vTb     = kb + 6291456;           // 64*96*1024 (transposed)
  u16* ctxb    = vTb + 6291456;          // 8192*768
  u16* wprojT  = ctxb + 6291456;         // 768*768

  prep_kernel<<<8448, 256, 0, stream>>>(x, w_qkv, w_proj, xb, wqkvT, wprojT);
  qkv_gemm_kernel<<<768, 256, 0, stream>>>(xb, wqkvT, temp, qb, kb, vTb);
  attn_kernel<<<512, 512, 0, stream>>>(qb, kb, vTb, ctxb);
  proj_gemm_kernel<<<768, 256, 0, stream>>>(ctxb, wprojT, b_proj, (float*)d_out);
}

// Round 8
// 178.261 us; speedup vs baseline: 1.0292x; 1.0133x over previous
//
#include <hip/hip_runtime.h>
#include <math.h>

typedef __attribute__((ext_vector_type(8))) short bf16x8;   // 8 bf16 = 4 VGPRs (MFMA A/B frag)
typedef __attribute__((ext_vector_type(4))) float f32x4;    // MFMA C/D frag
typedef __attribute__((ext_vector_type(4))) unsigned int u32x4;
typedef unsigned short u16;
typedef unsigned int u32;

// Problem: B=8, N=1024, C=768, H=8, hd=96.  BH=64 combined batch-heads.

__device__ __forceinline__ u16 f2b(float f) {               // fp32 -> bf16 RNE
  u32 u = __float_as_uint(f);
  return (u16)((u + 0x7fffu + ((u >> 16) & 1u)) >> 16);
}
__device__ __forceinline__ float b2f(u16 h) {
  return __uint_as_float(((u32)h) << 16);
}
__device__ __forceinline__ int swz(int m) { return (m ^ (m >> 2)) & 3; }

__device__ __forceinline__ void async16(const void* g, void* l) {
  __builtin_amdgcn_global_load_lds((const __attribute__((address_space(1))) u32*)g,
                                   (__attribute__((address_space(3))) u32*)l, 16, 0, 0);
}

// counted vmcnt waits (immediate must be literal in the asm string)
template<int N> __device__ __forceinline__ void wait_vmcnt();
template<> __device__ __forceinline__ void wait_vmcnt<0>() {
  asm volatile("s_waitcnt vmcnt(0)" ::: "memory");
}
template<> __device__ __forceinline__ void wait_vmcnt<3>() {
  asm volatile("s_waitcnt vmcnt(3)" ::: "memory");
}

// ---------------- prep: cast x, transpose+cast w_qkv and w_proj -------------
__global__ __launch_bounds__(256) void prep_kernel(const float* __restrict__ x,
                                                   const float* __restrict__ w_qkv,
                                                   const float* __restrict__ w_proj,
                                                   u16* __restrict__ xb,
                                                   u16* __restrict__ wqkvT,
                                                   u16* __restrict__ wprojT) {
  __shared__ float t[32][33];
  const int blk = blockIdx.x;
  if (blk < 6144) {                       // cast x -> bf16
    const int idx = blk * 256 + threadIdx.x;
    const float4 v = ((const float4*)x)[idx];
    uint2 o;
    o.x = (u32)f2b(v.x) | ((u32)f2b(v.y) << 16);
    o.y = (u32)f2b(v.z) | ((u32)f2b(v.w) << 16);
    ((uint2*)xb)[idx] = o;
    return;
  }
  const float* in; u16* out; int R, C, bx, by;
  if (blk < 6144 + 1728) {                // w_qkv [768,2304] -> [2304,768]
    const int rem = blk - 6144;
    in = w_qkv; out = wqkvT; R = 768; C = 2304; bx = rem % 72; by = rem / 72;
  } else {                                // w_proj [768,768] -> [768,768]
    const int rem = blk - 6144 - 1728;
    in = w_proj; out = wprojT; R = 768; C = 768; bx = rem % 24; by = rem / 24;
  }
  const int c0 = bx * 32, r0 = by * 32;
  const int tc = threadIdx.x & 31, tr = threadIdx.x >> 5;
#pragma unroll
  for (int j = 0; j < 4; ++j)
    t[tr + j * 8][tc] = in[(size_t)(r0 + tr + j * 8) * C + c0 + tc];
  __syncthreads();
#pragma unroll
  for (int j = 0; j < 4; ++j)
    out[(size_t)(c0 + tr + j * 8) * R + r0 + tc] = f2b(t[tc][tr + j * 8]);
}

// ---------------- BK=64 double-buffered GEMM core (qkv) ---------------------
// Round-7/8: per-K-step wall time is a ~1480-cycle latency floor that survived
// dbuf (r4), 8-wave (r5) and counted-vmcnt 3-buffer (r6) -- so AMORTIZE it:
// BK=64 halves the barrier count (12 iters), doubling MFMA+ds_read per
// barrier.  LDS 2 x 40KB = 80KB -> 2 blocks/CU (priced at ~+11% FETCH by
// r5/r6; the halved floor should dominate).
// Layout: 8 octets/row.  Granule slot s = row*8 + hp*4 + qd holds global
// octet (hp^(row&1))*4 + (qd^swz(row)) -- the parity bit keeps the b128
// read's bank spread at 8 lanes/quadrant (conflict-free, same analysis as
// the BK=32 layout).  Read: slot = row*8 + ((kk^(i15&1))<<2) + sw.
template<int NT>
__device__ __forceinline__ void gemm_core_bk64(const u16* __restrict__ A,
                                               const u16* __restrict__ Bt,
                                               int m0, int n0, f32x4 acc[4][NT / 32]) {
  constexpr int JT = NT / 32;
  constexpr int NG = (128 + NT) * 8;             // granules per K-tile
  constexpr int NINST = NG / 256;                // 10 for NT=192
  __shared__ u16 Sm[2 * NG * 8];
  const int tid = threadIdx.x;
  const int w = tid >> 6, lane = tid & 63;
  const int i15 = lane & 15, quad = lane >> 4;
  const int wm = (w >> 1) * 64, wn = (w & 1) * (NT / 2);
  const int sw = quad ^ swz(i15);
  const int par = i15 & 1;

#pragma unroll
  for (int i = 0; i < 4; ++i)
#pragma unroll
    for (int j = 0; j < JT; ++j) acc[i][j] = (f32x4){0.f, 0.f, 0.f, 0.f};

  // per-inst global source pointers at k0=0 (advance +64 per staged tile)
  const u16* gsrc[NINST];
#pragma unroll
  for (int inst = 0; inst < NINST; ++inst) {
    const int s = inst * 256 + tid;              // granule slot (per lane)
    if (s < 1024) {                              // A region: 128 rows x 8 octets
      const int m = s >> 3, hp = (s >> 2) & 1, qd = s & 3;
      const int e = (hp ^ (m & 1)) * 4 + (qd ^ swz(m));
      gsrc[inst] = A + ((size_t)(m0 + m) * 768 + e * 8);
    } else {                                     // B region: NT rows x 8 octets
      const int s2 = s - 1024;
      const int n = s2 >> 3, hp = (s2 >> 2) & 1, qd = s2 & 3;
      const int e = (hp ^ (n & 1)) * 4 + (qd ^ swz(n));
      gsrc[inst] = Bt + ((size_t)(n0 + n) * 768 + e * 8);
    }
  }

  auto stage = [&](int bsel) {
#pragma unroll
    for (int inst = 0; inst < NINST; ++inst) {
      async16(gsrc[inst], (void*)(Sm + ((size_t)bsel * NG + inst * 256 + w * 64) * 8));
      gsrc[inst] += 64;
    }
  };

  stage(0);                                      // prologue: K-tile 0 -> buf0

  for (int t = 0; t < 12; ++t) {
    __syncthreads();                             // implicit vmcnt(0): buf[t&1] ready
    if (t < 11) stage((t + 1) & 1);              // stage t+1 into other buffer
    const u16* buf = Sm + (size_t)(t & 1) * NG * 8;
#pragma unroll
    for (int kk = 0; kk < 2; ++kk) {             // two K=32 halves per tile
      bf16x8 af[4], bf[JT];
#pragma unroll
      for (int i = 0; i < 4; ++i) {
        const int mh = wm + i * 16 + i15;
        af[i] = *(const bf16x8*)(buf + ((size_t)mh * 8 + ((kk ^ par) << 2) + sw) * 8);
      }
#pragma unroll
      for (int j = 0; j < JT; ++j) {
        const int nh = wn + j * 16 + i15;
        bf[j] = *(const bf16x8*)(buf + ((size_t)1024 + nh * 8 + ((kk ^ par) << 2) + sw) * 8);
      }
#pragma unroll
      for (int i = 0; i < 4; ++i)
#pragma unroll
        for (int j = 0; j < JT; ++j)
          acc[i][j] = __builtin_amdgcn_mfma_f32_16x16x32_bf16(af[i], bf[j], acc[i][j], 0, 0, 0);
    }
  }
}

// ---------------- BK=32 3-buffer counted-vmcnt core (proj) ------------------
// Round-6 core, kept for proj where it measurably helped (36KB -> 4 blk/CU).
template<int NT>
__device__ __forceinline__ void gemm_core_c3(const u16* __restrict__ A,
                                             const u16* __restrict__ Bt,
                                             int m0, int n0, f32x4 acc[4][NT / 32]) {
  constexpr int JT = NT / 32;
  constexpr int NG = 512 + NT * 4;               // granules per K-tile
  constexpr int NINST = NG / 256;                // async16 per thread per tile
  __shared__ u16 Sm[3 * NG * 8];
  const int tid = threadIdx.x;
  const int w = tid >> 6, lane = tid & 63;
  const int i15 = lane & 15, quad = lane >> 4;
  const int wm = (w >> 1) * 64, wn = (w & 1) * (NT / 2);
  const int sw = quad ^ swz(i15);

#pragma unroll
  for (int i = 0; i < 4; ++i)
#pragma unroll
    for (int j = 0; j < JT; ++j) acc[i][j] = (f32x4){0.f, 0.f, 0.f, 0.f};

  const u16* gsrc[NINST];
#pragma unroll
  for (int inst = 0; inst < NINST; ++inst) {
    const int s = inst * 256 + tid;              // granule slot (per lane)
    if (s < 512) {                               // A region
      const int m = s >> 2, e = s & 3;
      gsrc[inst] = A + ((size_t)(m0 + m) * 768 + (e ^ swz(m)) * 8);
    } else {                                     // B region
      const int s2 = s - 512;
      const int n = s2 >> 2, e = s2 & 3;
      gsrc[inst] = Bt + ((size_t)(n0 + n) * 768 + (e ^ swz(n)) * 8);
    }
  }

  auto stage = [&](int bsel) {
#pragma unroll
    for (int inst = 0; inst < NINST; ++inst) {
      async16(gsrc[inst], (void*)(Sm + ((size_t)bsel * NG + inst * 256 + w * 64) * 8));
      gsrc[inst] += 32;
    }
  };

  stage(0);
  stage(1);

  for (int t = 0; t < 24; ++t) {
    if (t < 23) wait_vmcnt<NINST>();             // tile t landed; t+1 in flight
    else        wait_vmcnt<0>();                 // last tile: full drain
    __builtin_amdgcn_s_barrier();                // all waves' t-loads visible
    __builtin_amdgcn_sched_barrier(0);           // pin: nothing hoists above
    if (t < 22) stage((t + 2) % 3);              // out back to 2*NINST
    const u16* buf = Sm + (size_t)(t % 3) * NG * 8;
    bf16x8 af[4], bf[JT];
#pragma unroll
    for (int i = 0; i < 4; ++i)
      af[i] = *(const bf16x8*)(buf + ((size_t)(wm + i * 16 + i15) * 4 + sw) * 8);
#pragma unroll
    for (int j = 0; j < JT; ++j)
      bf[j] = *(const bf16x8*)(buf + ((size_t)512 + (wn + j * 16 + i15) * 4 + sw) * 8);
#pragma unroll
    for (int i = 0; i < 4; ++i)
#pragma unroll
      for (int j = 0; j < JT; ++j)
        acc[i][j] = __builtin_amdgcn_mfma_f32_16x16x32_bf16(af[i], bf[j], acc[i][j], 0, 0, 0);
  }
}

// ---------------- qkv GEMM + fused L2norm/temp epilogue ---------------------
// Tile 128x192: N-tile = exactly 2 heads -> each wave owns one head's full
// 96-d rows. Rows live in 16 lanes sharing quad -> sumsq = in-thread over jt
// + shfl_xor(1,2,4,8). q gets temp[h] folded; v written transposed (packed).
// BK=64 core: LDS 80KB -> 2 blocks/CU.
__global__ __launch_bounds__(256, 2) void qkv_gemm_kernel(
    const u16* __restrict__ xb, const u16* __restrict__ wT,
    const float* __restrict__ temp,
    u16* __restrict__ q, u16* __restrict__ k, u16* __restrict__ vT) {
  f32x4 acc[4][6];
  const int bid = blockIdx.x;                 // 768 blocks
  const int xcd = bid & 7, slot = bid >> 3;   // 96 slots per XCD
  const int mb = xcd * 8 + slot / 12, nb = slot % 12;
  const int m0 = mb * 128, n0 = nb * 192;
  gemm_core_bk64<192>(xb, wT, m0, n0, acc);

  const int tid = threadIdx.x, w = tid >> 6, lane = tid & 63;
  const int i15 = lane & 15, quad = lane >> 4;
  const int wm = (w >> 1) * 64;
  const int three = nb >> 2;                  // 0=q, 1=k, 2=v
  const int h = ((nb & 3) << 1) + (w & 1);    // wave-uniform head

  if (three < 2) {
    u16* dst = three ? k : q;
    const float sc_extra = three ? 1.f : temp[h];
#pragma unroll
    for (int it = 0; it < 4; ++it) {
#pragma unroll
      for (int r = 0; r < 4; ++r) {
        float s = 0.f;
#pragma unroll
        for (int jt = 0; jt < 6; ++jt) s += acc[it][jt][r] * acc[it][jt][r];
        s += __shfl_xor(s, 1); s += __shfl_xor(s, 2);
        s += __shfl_xor(s, 4); s += __shfl_xor(s, 8);
        const float scale = sc_extra / fmaxf(sqrtf(s), 1e-12f);
        const int m = m0 + wm + it * 16 + quad * 4 + r;
        const int b = m >> 10, n = m & 1023;
        u16* rowp = dst + ((size_t)(b * 8 + h) * 1024 + n) * 96;
#pragma unroll
        for (int jt = 0; jt < 6; ++jt)
          rowp[jt * 16 + i15] = f2b(acc[it][jt][r] * scale);
      }
    }
  } else {
#pragma unroll
    for (int it = 0; it < 4; ++it) {
      const int mb4 = m0 + wm + it * 16 + quad * 4;
      const int b = mb4 >> 10, nbase = mb4 & 1023;
#pragma unroll
      for (int jt = 0; jt < 6; ++jt) {
        const int d = jt * 16 + i15;
        uint2 pk;
        pk.x = (u32)f2b(acc[it][jt][0]) | ((u32)f2b(acc[it][jt][1]) << 16);
        pk.y = (u32)f2b(acc[it][jt][2]) | ((u32)f2b(acc[it][jt][3]) << 16);
        *(uint2*)(vT + ((size_t)(b * 8 + h) * 96 + d) * 1024 + nbase) = pk;
      }
    }
  }
}

// ---------------- fused attention, bf16 MFMA, no-max online softmax ---------
// 128 q-rows/block, grid 512, bh = blockIdx&63 (8 q-blocks of one bh share an
// XCD; K/V L2-resident ~3 MB/XCD).  512 threads = 8 waves x 16 q-rows.
// global_load_lds staging into DOUBLE-BUFFERED KV region, one barrier/tile.
// LDS: 2 x 12288 u16 KV buffers + 8 x 1024 u16 per-wave P = 64 KB -> 2 blk/CU.
// S^T = K*Q^T (C-regs = 4 consecutive keys) -> exp -> packed b64 into per-wave
// Ps -> PV with A=P, B=V^T. swz() granule XOR layouts.
__global__ __launch_bounds__(512, 4) void attn_kernel(
    const u16* __restrict__ q, const u16* __restrict__ kk,
    const u16* __restrict__ vT, u16* __restrict__ ctx) {
  __shared__ u16 smem[32768];   // [0,12288) buf0; [12288,24576) buf1; [24576,32768) P
  const int tid = threadIdx.x, w = tid >> 6, lane = tid & 63;
  const int i15 = lane & 15, quad = lane >> 4;
  const int xs = swz(i15);
  const int bh = blockIdx.x & 63, qbase = (blockIdx.x >> 6) * 128;
  const int b = bh >> 3, h = bh & 7;
  u16* Pw = smem + 24576 + w * 1024;   // per-wave P: 128 granules (16 rows x 64 keys)

  bf16x8 qf[3];
  {
    const int qrow = qbase + w * 16 + i15;
    const u16* qp = q + ((size_t)bh * 1024 + qrow) * 96 + quad * 8;
#pragma unroll
    for (int c = 0; c < 3; ++c) qf[c] = *(const bf16x8*)(qp + c * 32);
  }

  // Staging: 1536 granules/tile (K 768 + V 768), 3 async16 per thread.
  // Granule->global mapping is the inverse of the read-side formulas:
  //   K granule s<768:  c=s>>8, key=(s&255)>>2, qd=s&3 -> row key, octet c*4+(qd^swz(key))
  //   V granule s2:     r=s2>>2, c2=r>=96, d=r-96*c2, qd=s2&3 -> row d, key col c2*32+(qd^swz(d))*8
  const u16* gsrc[3]; int gstep[3];
#pragma unroll
  for (int inst = 0; inst < 3; ++inst) {
    const int s = inst * 512 + tid;
    if (s < 768) {
      const int key6 = (s & 255) >> 2, c = s >> 8;
      const int e = c * 4 + ((s & 3) ^ swz(key6));
      gsrc[inst] = kk + ((size_t)bh * 1024 + key6) * 96 + e * 8;
      gstep[inst] = 64 * 96;                 // +64 key rows per tile
    } else {
      const int s2 = s - 768, r = s2 >> 2;
      const int c2 = (r >= 96), d = r - 96 * c2;
      gsrc[inst] = vT + ((size_t)bh * 96 + d) * 1024 + c2 * 32 + ((s2 & 3) ^ swz(d)) * 8;
      gstep[inst] = 64;                      // +64 key cols per tile
    }
  }

  // prologue: stage tile 0 into buf0 (LDS dest is wave-uniform base + lane*16)
#pragma unroll
  for (int inst = 0; inst < 3; ++inst)
    async16(gsrc[inst], (void*)(smem + (size_t)(inst * 512 + w * 64) * 8));

  f32x4 o[6];
#pragma unroll
  for (int dt = 0; dt < 6; ++dt) o[dt] = (f32x4){0.f, 0.f, 0.f, 0.f};
  float l = 0.f;

  for (int t = 0; t < 16; ++t) {
    __syncthreads();                         // implicit vmcnt(0): buf[t&1] ready
    const u16* KVs = smem + (t & 1) * 12288;
    if (t < 15) {                            // stage t+1 into the other buffer
      u16* dst = smem + ((t + 1) & 1) * 12288;
#pragma unroll
      for (int inst = 0; inst < 3; ++inst) {
        gsrc[inst] += gstep[inst];
        async16(gsrc[inst], (void*)(dst + (size_t)(inst * 512 + w * 64) * 8));
      }
    }
    // ---- S^T phase ----
#pragma unroll
    for (int kt = 0; kt < 4; ++kt) {
      bf16x8 af[3];
#pragma unroll
      for (int c = 0; c < 3; ++c)
        af[c] = *(const bf16x8*)(KVs + ((size_t)((c * 64 + kt * 16 + i15) * 4) + (quad ^ xs)) * 8);
      f32x4 s = (f32x4){0.f, 0.f, 0.f, 0.f};
#pragma unroll
      for (int c = 0; c < 3; ++c)
        s = __builtin_amdgcn_mfma_f32_16x16x32_bf16(af[c], qf[c], s, 0, 0, 0);
      const float e0 = __expf(s[0]), e1 = __expf(s[1]);
      const float e2 = __expf(s[2]), e3 = __expf(s[3]);
      l += (e0 + e1) + (e2 + e3);
      uint2 pk;
      pk.x = (u32)f2b(e0) | ((u32)f2b(e1) << 16);
      pk.y = (u32)f2b(e2) | ((u32)f2b(e3) << 16);
      const int pg = (kt & 1) * 2 + (quad >> 1);
      *(uint2*)(Pw + (size_t)(((kt >> 1) * 16 + i15) * 4 + (pg ^ xs)) * 8
                    + (quad & 1) * 4) = pk;
    }
    // ---- PV phase ----
#pragma unroll
    for (int c2 = 0; c2 < 2; ++c2) {
      const bf16x8 pa = *(const bf16x8*)(Pw + (size_t)((c2 * 16 + i15) * 4 + (quad ^ xs)) * 8);
#pragma unroll
      for (int dt = 0; dt < 6; ++dt) {
        const bf16x8 vb = *(const bf16x8*)(KVs +
            ((size_t)(768 + (c2 * 96 + dt * 16 + i15) * 4) + (quad ^ xs)) * 8);
        o[dt] = __builtin_amdgcn_mfma_f32_16x16x32_bf16(pa, vb, o[dt], 0, 0, 0);
      }
    }
  }

  l += __shfl_xor(l, 16); l += __shfl_xor(l, 32);
  __syncthreads();                       // all waves done with KVs/Pw regions
  u16* scr = smem + w * 1664;            // 16 rows x stride 104 (per-wave)
#pragma unroll
  for (int r = 0; r < 4; ++r) {
    const float linv = 1.f / __shfl(l, quad * 4 + r);
    const int row16 = quad * 4 + r;
#pragma unroll
    for (int dt = 0; dt < 6; ++dt)
      scr[row16 * 104 + dt * 16 + i15] = f2b(o[dt][r] * linv);
  }
#pragma unroll
  for (int jj = 0; jj < 3; ++jj) {
    const int id = jj * 64 + lane;
    const int row16 = id / 12, g = id - row16 * 12;
    const int grow = b * 1024 + qbase + w * 16 + row16;
    *(uint4*)(ctx + (size_t)grow * 768 + h * 96 + g * 8) =
        *(const uint4*)(scr + row16 * 104 + g * 8);
  }
}

// ---------------- proj GEMM: 128x64 tiles, ctx @ wT + bias -> out fp32 ------
// 3-buffer counted-vmcnt core, LDS 36KB -> 4 blocks/CU (round-6, kept: total
// improved ~7us from this even as qkv regressed).
__global__ __launch_bounds__(256, 4) void proj_gemm_kernel(
    const u16* __restrict__ ctx, const u16* __restrict__ wT,
    const float* __restrict__ bias, float* __restrict__ out) {
  f32x4 acc[4][2];
  const int bid = blockIdx.x;                 // 768 blocks
  const int xcd = bid & 7, slot = bid >> 3;   // 96 slots per XCD
  const int mb = xcd * 8 + slot / 12, nb = slot % 12;
  const int m0 = mb * 128, n0 = nb * 64;
  gemm_core_c3<64>(ctx, wT, m0, n0, acc);

  const int tid = threadIdx.x, w = tid >> 6, lane = tid & 63;
  const int i15 = lane & 15, quad = lane >> 4;
  const int wm = (w >> 1) * 64, wn = (w & 1) * 32;
#pragma unroll
  for (int jt = 0; jt < 2; ++jt) {
    const int c = n0 + wn + jt * 16 + i15;
    const float bb = bias[c];
#pragma unroll
    for (int it = 0; it < 4; ++it) {
#pragma unroll
      for (int r = 0; r < 4; ++r) {
        const int m = m0 + wm + it * 16 + quad * 4 + r;
        out[(size_t)m * 768 + c] = acc[it][jt][r] + bb;
      }
    }
  }
}

// ---------------- host launcher --------------------------------------------
extern "C" void kernel_launch(void* const* d_in, const int* in_sizes, int n_in,
                              void* d_out, int out_size, void* d_ws, size_t ws_size,
                              hipStream_t stream) {
  const float* x      = (const float*)d_in[0];   // [8,1024,768]
  const float* w_qkv  = (const float*)d_in[1];   // [768,2304]
  const float* temp   = (const float*)d_in[2];   // [8]
  const float* w_proj = (const float*)d_in[3];   // [768,768]
  const float* b_proj = (const float*)d_in[4];   // [768]

  u16* ws      = (u16*)d_ws;
  u16* xb      = ws;                     // 8192*768
  u16* wqkvT   = xb + 6291456;           // 2304*768
  u16* qb      = wqkvT + 1769472;        // 64*1024*96
  u16* kb      = qb + 6291456;
  u16* vTb     = kb + 6291456;           // 64*96*1024 (transposed)
  u16* ctxb    = vTb + 6291456;          // 8192*768
  u16* wprojT  = ctxb + 6291456;         // 768*768

  prep_kernel<<<8448, 256, 0, stream>>>(x, w_qkv, w_proj, xb, wqkvT, wprojT);
  qkv_gemm_kernel<<<768, 256, 0, stream>>>(xb, wqkvT, temp, qb, kb, vTb);
  attn_kernel<<<512, 512, 0, stream>>>(qb, kb, vTb, ctxb);
  proj_gemm_kernel<<<768, 256, 0, stream>>>(ctxb, wprojT, b_proj, (float*)d_out);
}